// Round 4
// baseline (10460.890 us; speedup 1.0000x reference)
//
#include <hip/hip_runtime.h>
#include <hip/hip_bf16.h>

// CPC (CDCK2) full pipeline, round 4: workspace cut 442MB -> ~125MB.
// conv1 fused into stats1 + conv2 staging (z1 never materialized);
// buffers aliased by lifetime: bufA = z2->z4->gi, bufB = z3->z5.
// f32 VALU convs (implicit GEMM), train-mode BN folded into next-layer load,
// GRU with bf16 weights streamed from L2, tiny epilogue GEMMs + softmax/argmax.
// B=32, L=40960, CH=512, H=256, T=12; F: 8192/2048/1024/512/256.

using bf16 = __hip_bfloat16;

__device__ __forceinline__ float bf2f(bf16 v) { return __bfloat162float(v); }
__device__ __forceinline__ bf16 f2bf(float f) { return __float2bfloat16(f); }

// ---------------------------------------------------------------- BN1 stats (conv1 on the fly)
// block (b,c): z1[b][c][f] = sum_k x[b][5f-3+k]*w1[c][k] (zero-pad), reduce sum/sumsq.
__global__ __launch_bounds__(256) void stats1_kernel(
    const float* __restrict__ x, const float* __restrict__ w1, float* __restrict__ sums) {
  int bc = blockIdx.x;           // 32*512
  int b = bc >> 9, c = bc & 511;
  const float* xb = x + (size_t)b * 40960;
  float w[10];
#pragma unroll
  for (int k = 0; k < 10; ++k) w[k] = w1[c * 10 + k];
  float s = 0.f, q = 0.f;
  for (int f = threadIdx.x; f < 8192; f += 256) {
    int base = 5 * f - 3;
    float acc = 0.f;
#pragma unroll
    for (int k = 0; k < 10; ++k) {
      int xi = base + k;
      float xv = ((unsigned)xi < 40960u) ? xb[xi] : 0.f;
      acc = fmaf(xv, w[k], acc);
    }
    s += acc;
    q = fmaf(acc, acc, q);
  }
  __shared__ float rs[256], rq[256];
  rs[threadIdx.x] = s; rq[threadIdx.x] = q;
  __syncthreads();
  for (int w2_ = 128; w2_ > 0; w2_ >>= 1) {
    if (threadIdx.x < w2_) {
      rs[threadIdx.x] += rs[threadIdx.x + w2_];
      rq[threadIdx.x] += rq[threadIdx.x + w2_];
    }
    __syncthreads();
  }
  if (threadIdx.x == 0) {
    atomicAdd(&sums[c], rs[0]);
    atomicAdd(&sums[512 + c], rq[0]);
  }
}

// ---------------------------------------------------------------- BN stats (bf16 z)
__global__ __launch_bounds__(256) void stats_kernel(
    const bf16* __restrict__ z, int F, float* __restrict__ sums) {
  int bc = blockIdx.x;
  int c = bc & 511;
  const bf16* p = z + (size_t)bc * F;
  float s = 0.f, q = 0.f;
  for (int i = threadIdx.x; i < F; i += 256) {
    float v = bf2f(p[i]);
    s += v;
    q = fmaf(v, v, q);
  }
  __shared__ float rs[256], rq[256];
  rs[threadIdx.x] = s; rq[threadIdx.x] = q;
  __syncthreads();
  for (int w = 128; w > 0; w >>= 1) {
    if (threadIdx.x < w) {
      rs[threadIdx.x] += rs[threadIdx.x + w];
      rq[threadIdx.x] += rq[threadIdx.x + w];
    }
    __syncthreads();
  }
  if (threadIdx.x == 0) {
    atomicAdd(&sums[c], rs[0]);
    atomicAdd(&sums[512 + c], rq[0]);
  }
}

// mean/var -> per-channel affine a,b so next layer does relu(a*x+b).
__global__ void finalize_kernel(const float* __restrict__ sums, const float* __restrict__ g,
                                const float* __restrict__ be, float invN,
                                float* __restrict__ ab) {
  int c = threadIdx.x;  // 512 threads
  float mean = sums[c] * invN;
  float var = fmaf(-mean, mean, sums[512 + c] * invN);  // E[x^2]-E[x]^2 (biased)
  float a = g[c] * rsqrtf(var + 1e-5f);
  ab[c] = a;
  ab[512 + c] = fmaf(-mean, a, be[c]);
}

// ---------------------------------------------------------------- transpose
// out[c][r] = in[r][c]; builds wT[CI*K][CO] and wihT[CI][3H].
__global__ __launch_bounds__(256) void transpose_kernel(
    const float* __restrict__ in, float* __restrict__ out, int R, int C) {
  __shared__ float t[64][65];
  int c0 = blockIdx.x * 64, r0 = blockIdx.y * 64;
  int tx = threadIdx.x & 63, ty = threadIdx.x >> 6;
  for (int i = ty; i < 64; i += 4) {
    int r = r0 + i, c = c0 + tx;
    t[i][tx] = (r < R && c < C) ? in[(size_t)r * C + c] : 0.f;
  }
  __syncthreads();
  for (int i = ty; i < 64; i += 4) {
    int c = c0 + i, r = r0 + tx;
    if (c < C && r < R) out[(size_t)c * R + r] = t[tx][i];
  }
}

__global__ void cvt_bf16_kernel(const float* __restrict__ in, bf16* __restrict__ out, int n) {
  int i = blockIdx.x * 256 + threadIdx.x;
  if (i < n) out[i] = f2bf(in[i]);
}

// ---------------------------------------------------------------- conv2 (conv1 fused in staging)
// out z2[32][512][2048] bf16 raw. K=8,S=4,P=2; z1 recomputed from x in LDS.
__global__ __launch_bounds__(256) void conv2_fused_kernel(
    const float* __restrict__ x, const float* __restrict__ w1,
    const float* __restrict__ wT, const float* __restrict__ ab,
    bf16* __restrict__ out) {
  constexpr int SPAN = 63 * 4 + 8;        // 260 z1-elems per block
  constexpr int XW = 5 * (SPAN - 1) + 10; // 1305 x-elems window
  __shared__ float xl[1312];
  __shared__ float a_lds[8][SPAN];
  __shared__ float w_lds[8][8][128];
  int fo0 = blockIdx.x * 64;
  int co0 = blockIdx.y * 128;
  int b = blockIdx.z;
  int tid = threadIdx.x;
  int tx = tid & 15, ty = tid >> 4;
  int fi0 = fo0 * 4 - 2;      // z1-coord of a_lds[.][0]
  int x0 = 5 * fi0 - 3;       // x-coord of xl[0]
  const float* xb = x + (size_t)b * 40960;
  for (int i = tid; i < XW; i += 256) {
    int xi = x0 + i;
    xl[i] = ((unsigned)xi < 40960u) ? xb[xi] : 0.f;  // conv1 P=3 zero-pad
  }
  int sci = tid >> 5, sp = tid & 31;  // staging: group per ci, 32 lanes over p2
  float acc[4][8] = {};
  for (int ci0 = 0; ci0 < 512; ci0 += 8) {
    __syncthreads();
    float w1r[10];
#pragma unroll
    for (int k = 0; k < 10; ++k) w1r[k] = w1[(ci0 + sci) * 10 + k];
    float a1 = ab[ci0 + sci], b1 = ab[512 + ci0 + sci];
    for (int p2 = sp; p2 < SPAN; p2 += 32) {
      int fi = fi0 + p2;
      float v = 0.f;
      if ((unsigned)fi < 8192u) {  // conv2 zero-pad is AFTER bn+relu
        float s = 0.f;
        const float* xp = &xl[5 * p2];
#pragma unroll
        for (int k = 0; k < 10; ++k) s = fmaf(xp[k], w1r[k], s);
        v = fmaxf(fmaf(a1, s, b1), 0.f);
      }
      a_lds[sci][p2] = v;
    }
    for (int i = tid * 4; i < 8 * 1024; i += 1024) {
      int k = i >> 10;
      int r = i & 1023;
      int ci = r >> 7, co = r & 127;
      *(float4*)&w_lds[k][ci][co] =
          *(const float4*)&wT[((size_t)(ci0 + ci) * 8 + k) * 512 + co0 + co];
    }
    __syncthreads();
#pragma unroll
    for (int k = 0; k < 8; ++k) {
#pragma unroll
      for (int ci = 0; ci < 8; ++ci) {
        float av[4];
#pragma unroll
        for (int j = 0; j < 4; ++j) av[j] = a_lds[ci][(tx + 16 * j) * 4 + k];
        const float* wp = &w_lds[k][ci][ty * 8];
        float4 w0 = *(const float4*)wp;
        float4 w1v = *(const float4*)(wp + 4);
        float wv[8] = {w0.x, w0.y, w0.z, w0.w, w1v.x, w1v.y, w1v.z, w1v.w};
#pragma unroll
        for (int j = 0; j < 4; ++j)
#pragma unroll
          for (int cc = 0; cc < 8; ++cc)
            acc[j][cc] = fmaf(av[j], wv[cc], acc[j][cc]);
      }
    }
  }
#pragma unroll
  for (int j = 0; j < 4; ++j)
#pragma unroll
    for (int cc = 0; cc < 8; ++cc)
      out[((size_t)b * 512 + co0 + ty * 8 + cc) * 2048 + fo0 + tx + 16 * j] =
          f2bf(acc[j][cc]);
}

// ---------------------------------------------------------------- generic conv (layers 3-5)
// in[B][512][Fi] bf16 raw; applies relu(a*x+b) on load; wT[(ci*K+k)][512] f32;
// out[B][512][Fo] bf16 raw. Tile 64fo x 128co, 256 thr, 4x8 reg blocking.
template <int K, int S, int P>
__global__ __launch_bounds__(256) void conv_kernel(
    const bf16* __restrict__ in, const float* __restrict__ wT,
    const float* __restrict__ ab, bf16* __restrict__ out, int Fi, int Fo) {
  constexpr int SPAN = 63 * S + K;
  __shared__ float a_lds[8][SPAN];
  __shared__ float w_lds[K][8][128];
  int fo0 = blockIdx.x * 64;
  int co0 = blockIdx.y * 128;
  int b = blockIdx.z;
  int tid = threadIdx.x;
  int tx = tid & 15, ty = tid >> 4;
  int fi0 = fo0 * S - P;
  float acc[4][8] = {};
  for (int ci0 = 0; ci0 < 512; ci0 += 8) {
    __syncthreads();
    for (int i = tid; i < 8 * SPAN; i += 256) {
      int ci = i / SPAN, p2 = i % SPAN;
      int fi = fi0 + p2;
      float v = 0.f;
      if (fi >= 0 && fi < Fi) {
        float xv = bf2f(in[((size_t)b * 512 + ci0 + ci) * Fi + fi]);
        v = fmaxf(fmaf(ab[ci0 + ci], xv, ab[512 + ci0 + ci]), 0.f);
      }
      a_lds[ci][p2] = v;
    }
    for (int i = tid * 4; i < K * 1024; i += 1024) {
      int k = i >> 10;
      int r = i & 1023;
      int ci = r >> 7, co = r & 127;
      *(float4*)&w_lds[k][ci][co] =
          *(const float4*)&wT[((size_t)(ci0 + ci) * K + k) * 512 + co0 + co];
    }
    __syncthreads();
#pragma unroll
    for (int k = 0; k < K; ++k) {
#pragma unroll
      for (int ci = 0; ci < 8; ++ci) {
        float av[4];
#pragma unroll
        for (int j = 0; j < 4; ++j) av[j] = a_lds[ci][(tx + 16 * j) * S + k];
        const float* wp = &w_lds[k][ci][ty * 8];
        float4 w0 = *(const float4*)wp;
        float4 w1 = *(const float4*)(wp + 4);
        float wv[8] = {w0.x, w0.y, w0.z, w0.w, w1.x, w1.y, w1.z, w1.w};
#pragma unroll
        for (int j = 0; j < 4; ++j)
#pragma unroll
          for (int cc = 0; cc < 8; ++cc)
            acc[j][cc] = fmaf(av[j], wv[cc], acc[j][cc]);
      }
    }
  }
#pragma unroll
  for (int j = 0; j < 4; ++j)
#pragma unroll
    for (int cc = 0; cc < 8; ++cc)
      out[((size_t)b * 512 + co0 + ty * 8 + cc) * Fo + fo0 + tx + 16 * j] =
          f2bf(acc[j][cc]);
}

// ---------------------------------------------------------------- gi GEMM
// gi[b][t][j] = sum_ci relu(a5*z5[b][ci][t]+b5) * wih[j][ci] + bih[j]
__global__ __launch_bounds__(256) void gi_kernel(
    const bf16* __restrict__ z5, const float* __restrict__ wihT,
    const float* __restrict__ bih, const float* __restrict__ ab,
    float* __restrict__ gi) {
  __shared__ float a_lds[8][64];
  __shared__ float w_lds[8][128];
  int t0 = blockIdx.x * 64, j0 = blockIdx.y * 128, b = blockIdx.z;
  int tid = threadIdx.x, tx = tid & 15, ty = tid >> 4;
  float acc[4][8] = {};
  for (int ci0 = 0; ci0 < 512; ci0 += 8) {
    __syncthreads();
    for (int i = tid; i < 512; i += 256) {
      int ci = i >> 6, t = i & 63;
      float v = bf2f(z5[((size_t)b * 512 + ci0 + ci) * 256 + t0 + t]);
      a_lds[ci][t] = fmaxf(fmaf(ab[ci0 + ci], v, ab[512 + ci0 + ci]), 0.f);
    }
    {
      int i = tid * 4;  // 1024 elems exactly
      int ci = i >> 7, j = i & 127;
      *(float4*)&w_lds[ci][j] = *(const float4*)&wihT[(size_t)(ci0 + ci) * 768 + j0 + j];
    }
    __syncthreads();
#pragma unroll
    for (int ci = 0; ci < 8; ++ci) {
      float av[4];
#pragma unroll
      for (int j = 0; j < 4; ++j) av[j] = a_lds[ci][tx + 16 * j];
      const float* wp = &w_lds[ci][ty * 8];
      float4 w0 = *(const float4*)wp;
      float4 w1 = *(const float4*)(wp + 4);
      float wv[8] = {w0.x, w0.y, w0.z, w0.w, w1.x, w1.y, w1.z, w1.w};
#pragma unroll
      for (int j = 0; j < 4; ++j)
#pragma unroll
        for (int cc = 0; cc < 8; ++cc)
          acc[j][cc] = fmaf(av[j], wv[cc], acc[j][cc]);
    }
  }
  float bv[8];
#pragma unroll
  for (int cc = 0; cc < 8; ++cc) bv[cc] = bih[j0 + ty * 8 + cc];
#pragma unroll
  for (int j = 0; j < 4; ++j) {
    int row = t0 + tx + 16 * j;
    float4 s0 = {acc[j][0] + bv[0], acc[j][1] + bv[1], acc[j][2] + bv[2], acc[j][3] + bv[3]};
    float4 s1 = {acc[j][4] + bv[4], acc[j][5] + bv[5], acc[j][6] + bv[6], acc[j][7] + bv[7]};
    float* gp = &gi[((size_t)b * 256 + row) * 768 + j0 + ty * 8];
    *(float4*)gp = s0;
    *(float4*)(gp + 4) = s1;
  }
}

// ---------------------------------------------------------------- GRU
__device__ __forceinline__ void dot8(float& d, float4 h0, float4 h1, uint4 u) {
  d = fmaf(h0.x, __uint_as_float(u.x << 16), d);
  d = fmaf(h0.y, __uint_as_float(u.x & 0xffff0000u), d);
  d = fmaf(h0.z, __uint_as_float(u.y << 16), d);
  d = fmaf(h0.w, __uint_as_float(u.y & 0xffff0000u), d);
  d = fmaf(h1.x, __uint_as_float(u.z << 16), d);
  d = fmaf(h1.y, __uint_as_float(u.z & 0xffff0000u), d);
  d = fmaf(h1.z, __uint_as_float(u.w << 16), d);
  d = fmaf(h1.w, __uint_as_float(u.w & 0xffff0000u), d);
}

// one block per batch; h (f32) in LDS (broadcast reads = conflict-free);
// whh bf16 streamed from L2 each step; runs only to t_samples[b].
__global__ __launch_bounds__(256) void gru_kernel(
    const float* __restrict__ gi, const bf16* __restrict__ whhb,
    const float* __restrict__ bhh, const int* __restrict__ tsamp,
    float* __restrict__ c_t) {
  int b = blockIdx.x;
  int j = threadIdx.x;
  __shared__ float h[256];
  h[j] = 0.f;
  int Tb = tsamp[b];
  float bhr = bhh[j], bhz = bhh[256 + j], bhn = bhh[512 + j];
  const float* gib = gi + (size_t)b * 256 * 768;
  const uint4* wr = (const uint4*)(whhb + (size_t)j * 256);
  const uint4* wz = (const uint4*)(whhb + (size_t)(256 + j) * 256);
  const uint4* wn = (const uint4*)(whhb + (size_t)(512 + j) * 256);
  __syncthreads();
  for (int t = 0; t <= Tb; ++t) {
    const float* git = gib + t * 768;
    float dr = 0.f, dz = 0.f, dn = 0.f;
#pragma unroll 4
    for (int c8 = 0; c8 < 32; ++c8) {
      float4 h0 = *(const float4*)&h[c8 * 8];
      float4 h1 = *(const float4*)&h[c8 * 8 + 4];
      dot8(dr, h0, h1, wr[c8]);
      dot8(dz, h0, h1, wz[c8]);
      dot8(dn, h0, h1, wn[c8]);
    }
    float xr_ = git[j], xz_ = git[256 + j], xn_ = git[512 + j];
    float r = 1.f / (1.f + __expf(-(xr_ + dr + bhr)));
    float zg = 1.f / (1.f + __expf(-(xz_ + dz + bhz)));
    float n = tanhf(fmaf(r, dn + bhn, xn_));
    float hj = h[j];
    float hnew = fmaf(zg, hj - n, n);  // (1-z)n + z*h
    __syncthreads();
    h[j] = hnew;
    __syncthreads();
  }
  c_t[b * 256 + j] = h[j];
}

// ---------------------------------------------------------------- pred
__global__ __launch_bounds__(256) void pred_kernel(
    const float* __restrict__ c_t, const float* __restrict__ wk,
    const float* __restrict__ bk, float* __restrict__ pred) {
  int tp = blockIdx.x >> 5, c = blockIdx.x & 31;
  __shared__ float cl[256];
  cl[threadIdx.x] = c_t[c * 256 + threadIdx.x];
  __syncthreads();
  const float* wkt = wk + (size_t)tp * 512 * 256;
  for (int d = threadIdx.x; d < 512; d += 256) {
    float a = bk[tp * 512 + d];
    const float* w = wkt + (size_t)d * 256;
    for (int hh = 0; hh < 256; hh += 4) {
      float4 wv = *(const float4*)&w[hh];
      a = fmaf(wv.x, cl[hh], a);
      a = fmaf(wv.y, cl[hh + 1], a);
      a = fmaf(wv.z, cl[hh + 2], a);
      a = fmaf(wv.w, cl[hh + 3], a);
    }
    pred[((size_t)tp * 32 + c) * 512 + d] = a;
  }
}

// ---------------------------------------------------------------- totals
__global__ __launch_bounds__(256) void totals_kernel(
    const bf16* __restrict__ z5, const float* __restrict__ ab,
    const int* __restrict__ tsamp, const float* __restrict__ pred,
    float* __restrict__ totals) {
  int tp = blockIdx.x >> 5, b = blockIdx.x & 31;
  __shared__ float el[512];
  __shared__ float red[256];
  int tb = tsamp[b] + 1 + tp;
  for (int d = threadIdx.x; d < 512; d += 256) {
    float v = bf2f(z5[((size_t)b * 512 + d) * 256 + tb]);
    el[d] = fmaxf(fmaf(ab[d], v, ab[512 + d]), 0.f);
  }
  __syncthreads();
  int c = threadIdx.x & 31, chunk = threadIdx.x >> 5;
  const float* pr = pred + ((size_t)tp * 32 + c) * 512 + chunk * 64;
  const float* ep = &el[chunk * 64];
  float a = 0.f;
#pragma unroll 8
  for (int d = 0; d < 64; ++d) a = fmaf(pr[d], ep[d], a);
  red[threadIdx.x] = a;
  __syncthreads();
  if (threadIdx.x < 32) {
    float s = 0.f;
#pragma unroll
    for (int k = 0; k < 8; ++k) s += red[k * 32 + threadIdx.x];
    totals[((size_t)tp * 32 + b) * 32 + threadIdx.x] = s;
  }
}

// ---------------------------------------------------------------- final
// nce = sum_t,b lsm[t,b,b] / (-B*T); preds = column argmax of row-LSE-adjusted logits.
__global__ __launch_bounds__(384) void final_kernel(const float* __restrict__ totals,
                                                    float* __restrict__ out) {
  __shared__ float adj[12 * 32 * 32];
  __shared__ float tr_red[384];
  __shared__ int cr_red[384];
  int tid = threadIdx.x;  // 384 = 12*32
  for (int i = tid; i < 12288; i += 384) adj[i] = totals[i];
  __syncthreads();
  int tp = tid / 32, b = tid % 32;
  float* row = &adj[(tp * 32 + b) * 32];
  float mx = row[0];
#pragma unroll
  for (int c = 1; c < 32; ++c) mx = fmaxf(mx, row[c]);
  float se = 0.f;
  for (int c = 0; c < 32; ++c) se += expf(row[c] - mx);
  float lse = mx + logf(se);
  float tr = row[b] - lse;
  __syncthreads();
  for (int c = 0; c < 32; ++c) row[c] -= lse;
  __syncthreads();
  int c = b;  // this thread also handles column (tp, c)
  float best = adj[(tp * 32 + 0) * 32 + c];
  int bi = 0;
  for (int bb = 1; bb < 32; ++bb) {
    float v = adj[(tp * 32 + bb) * 32 + c];
    if (v > best) { best = v; bi = bb; }
  }
  tr_red[tid] = tr;
  cr_red[tid] = (bi == c) ? 1 : 0;
  __syncthreads();
  if (tid == 0) {
    float ts_ = 0.f;
    int cs = 0;
    for (int i = 0; i < 384; ++i) { ts_ += tr_red[i]; cs += cr_red[i]; }
    out[0] = (float)cs / 32.0f;      // accuracy = correct / B
    out[1] = ts_ / (-384.0f);        // nce = trace.sum() / (-B*T)
  }
}

// ================================================================ launcher
extern "C" void kernel_launch(void* const* d_in, const int* in_sizes, int n_in,
                              void* d_out, int out_size, void* d_ws, size_t ws_size,
                              hipStream_t stream) {
  const float* x = (const float*)d_in[0];
  const int* tsamp = (const int*)d_in[1];
  const float* w1 = (const float*)d_in[2];
  const float* w2 = (const float*)d_in[3];
  const float* w3 = (const float*)d_in[4];
  const float* w4 = (const float*)d_in[5];
  const float* w5 = (const float*)d_in[6];
  const float* gg[5] = {(const float*)d_in[7], (const float*)d_in[9], (const float*)d_in[11],
                        (const float*)d_in[13], (const float*)d_in[15]};
  const float* bee[5] = {(const float*)d_in[8], (const float*)d_in[10], (const float*)d_in[12],
                         (const float*)d_in[14], (const float*)d_in[16]};
  const float* wih = (const float*)d_in[17];
  const float* whh = (const float*)d_in[18];
  const float* bih = (const float*)d_in[19];
  const float* bhh = (const float*)d_in[20];
  const float* wk = (const float*)d_in[21];
  const float* bk = (const float*)d_in[22];
  float* out = (float*)d_out;

  char* base = (char*)d_ws;
  size_t off = 0;
  auto alloc = [&](size_t bytes) -> char* {
    char* r = base + off;
    off = (off + bytes + 255) & ~(size_t)255;
    return r;
  };
  // bufA (67.1MB): z2 -> z4 -> gi.  bufB (33.6MB): z3 -> z5.
  char* bufA = alloc((size_t)33554432 * 2);   // 32*512*2048 bf16
  char* bufB = alloc((size_t)16777216 * 2);   // 32*512*1024 bf16
  bf16* z2 = (bf16*)bufA;
  bf16* z3 = (bf16*)bufB;
  bf16* z4 = (bf16*)bufA;                     // alive only conv4..conv5
  bf16* z5 = (bf16*)bufB;                     // alive conv5..totals (z3 dead)
  float* gi = (float*)bufA;                   // alive gi_kernel..gru (z4 dead)
  float* wT2 = (float*)alloc((size_t)2097152 * 4);  // [4096][512]
  float* wT3 = (float*)alloc((size_t)1048576 * 4);  // [2048][512]
  float* wT4 = (float*)alloc((size_t)1048576 * 4);
  float* wT5 = (float*)alloc((size_t)1048576 * 4);
  float* wihT = (float*)alloc((size_t)393216 * 4);  // [512][768]
  bf16* whhb = (bf16*)alloc((size_t)196608 * 2);
  float* stats = (float*)alloc(5 * 1024 * 4);
  float* ab = (float*)alloc(5 * 1024 * 4);
  float* ct = (float*)alloc(8192 * 4);
  float* pred = (float*)alloc(196608 * 4);
  float* totals = (float*)alloc(12288 * 4);
  (void)ws_size;  // total footprint ~125MB

  hipMemsetAsync(stats, 0, 5 * 1024 * 4, stream);

  transpose_kernel<<<dim3(64, 8), 256, 0, stream>>>(w2, wT2, 512, 4096);
  transpose_kernel<<<dim3(32, 8), 256, 0, stream>>>(w3, wT3, 512, 2048);
  transpose_kernel<<<dim3(32, 8), 256, 0, stream>>>(w4, wT4, 512, 2048);
  transpose_kernel<<<dim3(32, 8), 256, 0, stream>>>(w5, wT5, 512, 2048);
  transpose_kernel<<<dim3(8, 12), 256, 0, stream>>>(wih, wihT, 768, 512);
  cvt_bf16_kernel<<<768, 256, 0, stream>>>(whh, whhb, 196608);

  stats1_kernel<<<16384, 256, 0, stream>>>(x, w1, stats);
  finalize_kernel<<<1, 512, 0, stream>>>(stats, gg[0], bee[0], 1.f / 262144.f, ab);

  conv2_fused_kernel<<<dim3(32, 4, 32), 256, 0, stream>>>(x, w1, wT2, ab, z2);
  stats_kernel<<<16384, 256, 0, stream>>>(z2, 2048, stats + 1024);
  finalize_kernel<<<1, 512, 0, stream>>>(stats + 1024, gg[1], bee[1], 1.f / 65536.f, ab + 1024);

  conv_kernel<4, 2, 1><<<dim3(16, 4, 32), 256, 0, stream>>>(z2, wT3, ab + 1024, z3, 2048, 1024);
  stats_kernel<<<16384, 256, 0, stream>>>(z3, 1024, stats + 2048);
  finalize_kernel<<<1, 512, 0, stream>>>(stats + 2048, gg[2], bee[2], 1.f / 32768.f, ab + 2048);

  conv_kernel<4, 2, 1><<<dim3(8, 4, 32), 256, 0, stream>>>(z3, wT4, ab + 2048, z4, 1024, 512);
  stats_kernel<<<16384, 256, 0, stream>>>(z4, 512, stats + 3072);
  finalize_kernel<<<1, 512, 0, stream>>>(stats + 3072, gg[3], bee[3], 1.f / 16384.f, ab + 3072);

  conv_kernel<4, 2, 1><<<dim3(4, 4, 32), 256, 0, stream>>>(z4, wT5, ab + 3072, z5, 512, 256);
  stats_kernel<<<16384, 256, 0, stream>>>(z5, 256, stats + 4096);
  finalize_kernel<<<1, 512, 0, stream>>>(stats + 4096, gg[4], bee[4], 1.f / 8192.f, ab + 4096);

  gi_kernel<<<dim3(4, 6, 32), 256, 0, stream>>>(z5, wihT, bih, ab + 4096, gi);
  gru_kernel<<<32, 256, 0, stream>>>(gi, whhb, bhh, tsamp, ct);
  pred_kernel<<<384, 256, 0, stream>>>(ct, wk, bk, pred);
  totals_kernel<<<384, 256, 0, stream>>>(z5, ab + 4096, tsamp, pred, totals);
  final_kernel<<<1, 384, 0, stream>>>(totals, out);
}

// Round 5
// 3950.397 us; speedup vs baseline: 2.6481x; 2.6481x over previous
//
#include <hip/hip_runtime.h>
#include <hip/hip_bf16.h>

// CPC (CDCK2) round 5: MFMA bf16 convs (128x128 tile, 16x16x32), coalesced GRU,
// shared-x stats1. Workspace ~155MB via slab aliasing.
// B=32, L=40960, CH=512, H=256, T=12; F: 8192/2048/1024/512/256.

using bf16 = __hip_bfloat16;
typedef __attribute__((ext_vector_type(8))) short bf16x8;
typedef __attribute__((ext_vector_type(4))) float f32x4;

__device__ __forceinline__ float bf2f(bf16 v) { return __bfloat162float(v); }
__device__ __forceinline__ bf16 f2bf(float f) { return __float2bfloat16(f); }
__device__ __forceinline__ ushort bfbits(float f) {
  bf16 b = f2bf(f);
  return *reinterpret_cast<ushort*>(&b);
}
union FragU { uint4 u; bf16x8 v; };

// ---------------------------------------------------------------- stats1 (conv1 on the fly, x in LDS)
// grid (16 fslices, 32 b); each block: all 512 c over 512 f.
__global__ __launch_bounds__(256) void stats1_kernel(
    const float* __restrict__ x, const float* __restrict__ w1, float* __restrict__ sums) {
  __shared__ float xs[2576];
  int s = blockIdx.x, b = blockIdx.y;
  const float* xb = x + (size_t)b * 40960;
  int w0 = 2560 * s - 3;
  for (int i = threadIdx.x; i < 2565; i += 256) {
    int xi = w0 + i;
    xs[i] = ((unsigned)xi < 40960u) ? xb[xi] : 0.f;
  }
  __syncthreads();
  int c0 = threadIdx.x, c1 = threadIdx.x + 256;
  float wA[10], wB[10];
#pragma unroll
  for (int k = 0; k < 10; ++k) { wA[k] = w1[c0 * 10 + k]; wB[k] = w1[c1 * 10 + k]; }
  float sA = 0.f, qA = 0.f, sB = 0.f, qB = 0.f;
  for (int f = 0; f < 512; ++f) {
    const float* xp = &xs[5 * f];
    float aA = 0.f, aB = 0.f;
#pragma unroll
    for (int k = 0; k < 10; ++k) {
      float xv = xp[k];
      aA = fmaf(xv, wA[k], aA);
      aB = fmaf(xv, wB[k], aB);
    }
    sA += aA; qA = fmaf(aA, aA, qA);
    sB += aB; qB = fmaf(aB, aB, qB);
  }
  atomicAdd(&sums[c0], sA); atomicAdd(&sums[512 + c0], qA);
  atomicAdd(&sums[c1], sB); atomicAdd(&sums[512 + c1], qB);
}

// ---------------------------------------------------------------- BN stats (bf16 z)
__global__ __launch_bounds__(256) void stats_kernel(
    const bf16* __restrict__ z, int F, float* __restrict__ sums) {
  int bc = blockIdx.x;
  int c = bc & 511;
  const bf16* p = z + (size_t)bc * F;
  float s = 0.f, q = 0.f;
  for (int i = threadIdx.x; i < F; i += 256) {
    float v = bf2f(p[i]);
    s += v;
    q = fmaf(v, v, q);
  }
  __shared__ float rs[256], rq[256];
  rs[threadIdx.x] = s; rq[threadIdx.x] = q;
  __syncthreads();
  for (int w = 128; w > 0; w >>= 1) {
    if (threadIdx.x < w) {
      rs[threadIdx.x] += rs[threadIdx.x + w];
      rq[threadIdx.x] += rq[threadIdx.x + w];
    }
    __syncthreads();
  }
  if (threadIdx.x == 0) {
    atomicAdd(&sums[c], rs[0]);
    atomicAdd(&sums[512 + c], rq[0]);
  }
}

__global__ void finalize_kernel(const float* __restrict__ sums, const float* __restrict__ g,
                                const float* __restrict__ be, float invN,
                                float* __restrict__ ab) {
  int c = threadIdx.x;  // 512
  float mean = sums[c] * invN;
  float var = fmaf(-mean, mean, sums[512 + c] * invN);
  float a = g[c] * rsqrtf(var + 1e-5f);
  ab[c] = a;
  ab[512 + c] = fmaf(-mean, a, be[c]);
}

// ---------------------------------------------------------------- transpose (wih only)
__global__ __launch_bounds__(256) void transpose_kernel(
    const float* __restrict__ in, float* __restrict__ out, int R, int C) {
  __shared__ float t[64][65];
  int c0 = blockIdx.x * 64, r0 = blockIdx.y * 64;
  int tx = threadIdx.x & 63, ty = threadIdx.x >> 6;
  for (int i = ty; i < 64; i += 4) {
    int r = r0 + i, c = c0 + tx;
    t[i][tx] = (r < R && c < C) ? in[(size_t)r * C + c] : 0.f;
  }
  __syncthreads();
  for (int i = ty; i < 64; i += 4) {
    int c = c0 + i, r = r0 + tx;
    if (c < C && r < R) out[(size_t)c * R + r] = t[tx][i];
  }
}

__global__ void cvt_bf16_kernel(const float* __restrict__ in, bf16* __restrict__ out, int n) {
  int i = blockIdx.x * 256 + threadIdx.x;
  if (i < n) out[i] = f2bf(in[i]);
}

// pack whh rows into [128 c-pairs][768] uints for coalesced GRU reads
__global__ void pack_whh_kernel(const float* __restrict__ whh, uint* __restrict__ P) {
  int idx = blockIdx.x * 256 + threadIdx.x;
  if (idx < 98304) {
    int p = idx / 768, gj = idx % 768;
    float lo = whh[(size_t)gj * 256 + 2 * p];
    float hi = whh[(size_t)gj * 256 + 2 * p + 1];
    P[idx] = (uint)bfbits(lo) | ((uint)bfbits(hi) << 16);
  }
}

// ---------------------------------------------------------------- norm1 (conv1+BN1+ReLU -> padded bf16)
// zn chunk layout: [8 b][512 c][8208] with data at idx 6+fi, zero pads.
__global__ __launch_bounds__(256) void norm1_kernel(
    const float* __restrict__ x, const float* __restrict__ w1,
    const float* __restrict__ ab, bf16* __restrict__ zn, int chunk0) {
  __shared__ float xs[1312];
  int s = blockIdx.x, bl = blockIdx.y;
  int pidx = s * 256 + threadIdx.x;
  const float* xb = x + (size_t)(chunk0 + bl) * 40960;
  int w0 = 1280 * s - 33;
  for (int i = threadIdx.x; i < 1285; i += 256) {
    int xi = w0 + i;
    xs[i] = ((unsigned)xi < 40960u) ? xb[xi] : 0.f;
  }
  __syncthreads();
  if (pidx >= 8208) return;
  int fi = pidx - 6;
  bool inb = ((unsigned)fi < 8192u);
  const float* xp = &xs[5 * threadIdx.x];
  bf16* zp = zn + (size_t)bl * 512 * 8208 + pidx;
  for (int c = 0; c < 512; ++c) {
    float v = 0.f;
    if (inb) {
      float acc = 0.f;
      const float* w = &w1[c * 10];
#pragma unroll
      for (int k = 0; k < 10; ++k) acc = fmaf(xp[k], w[k], acc);
      v = fmaxf(fmaf(ab[c], acc, ab[512 + c]), 0.f);
    }
    zp[(size_t)c * 8208] = f2bf(v);
  }
}

// ---------------------------------------------------------------- conv2 MFMA
// A: z1n padded normalized bf16 [8][512][8208]; B: wB2 bf16 [512][4096] (=w2 flat);
// out: z2raw [32][512][2048] bf16. Tile 128fo x 128co, BK=32 (4 ci x 8 kk), 4 waves.
__global__ __launch_bounds__(256) void conv2_mfma(
    const bf16* __restrict__ zn, const bf16* __restrict__ wB,
    bf16* __restrict__ out, int chunk0) {
  __shared__ ushort aL[4][520];     // span 516, pad 520
  __shared__ ushort bL[128][36];    // 32 k, pad 36
  int fo0 = blockIdx.x * 128, co0 = blockIdx.y * 128, bl = blockIdx.z;
  int tid = threadIdx.x;
  int w = tid >> 6, l = tid & 63;
  int m0 = (w >> 1) * 64, n0 = (w & 1) * 64;
  int row = l & 15, kq = l >> 4;
  f32x4 acc[4][4];
#pragma unroll
  for (int i = 0; i < 4; ++i)
#pragma unroll
    for (int j = 0; j < 4; ++j) acc[i][j] = {0.f, 0.f, 0.f, 0.f};
  const ushort* zb = (const ushort*)zn + (size_t)bl * 512 * 8208;
  int astart = 4 * fo0 + 4;  // padded idx of fi0 = 4*fo0-2 (LP=6)
  int sco = tid >> 1, shalf = tid & 1;
  for (int step = 0; step < 128; ++step) {
    int ci0 = step * 4;
    int k0 = step * 32;
    __syncthreads();
    for (int u = tid; u < 520; u += 256) {
      int ci = u / 130, off = (u % 130) * 4;
      *(uint2*)&aL[ci][off] =
          *(const uint2*)(zb + (size_t)(ci0 + ci) * 8208 + astart + off);
    }
    {
      const uint2* src = (const uint2*)(wB + (size_t)(co0 + sco) * 4096 + k0 + shalf * 16);
      uint2* dst = (uint2*)&bL[sco][shalf * 16];
      dst[0] = src[0]; dst[1] = src[1]; dst[2] = src[2]; dst[3] = src[3];
    }
    __syncthreads();
    bf16x8 af[4], bfr[4];
#pragma unroll
    for (int mi = 0; mi < 4; ++mi) {
      int am = (m0 + mi * 16 + row) * 4;
      const uint2* ap = (const uint2*)((const char*)&aL[0][0] + kq * 1040 + am * 2);
      uint2 a0 = ap[0], a1 = ap[1];
      FragU f; f.u = make_uint4(a0.x, a0.y, a1.x, a1.y);
      af[mi] = f.v;
    }
#pragma unroll
    for (int ni = 0; ni < 4; ++ni) {
      int col = n0 + ni * 16 + row;
      const uint2* bp = (const uint2*)((const char*)&bL[0][0] + col * 72 + kq * 16);
      uint2 b0 = bp[0], b1 = bp[1];
      FragU f; f.u = make_uint4(b0.x, b0.y, b1.x, b1.y);
      bfr[ni] = f.v;
    }
#pragma unroll
    for (int mi = 0; mi < 4; ++mi)
#pragma unroll
      for (int ni = 0; ni < 4; ++ni)
        acc[mi][ni] = __builtin_amdgcn_mfma_f32_16x16x32_bf16(af[mi], bfr[ni], acc[mi][ni], 0, 0, 0);
  }
  size_t ob = (size_t)(chunk0 + bl) * 512;
#pragma unroll
  for (int mi = 0; mi < 4; ++mi)
#pragma unroll
    for (int ni = 0; ni < 4; ++ni)
#pragma unroll
      for (int r = 0; r < 4; ++r) {
        int m = m0 + mi * 16 + kq * 4 + r;
        int n = n0 + ni * 16 + row;
        out[(ob + co0 + n) * 2048 + fo0 + m] = f2bf(acc[mi][ni][r]);
      }
}

// ---------------------------------------------------------------- convN MFMA (K=4,S=2,P=1; layers 3-5)
// A: raw bf16 [32][512][Fi], BN+ReLU applied in staging; B: wB bf16 [512][2048].
__global__ __launch_bounds__(256) void convN_mfma(
    const bf16* __restrict__ in, const bf16* __restrict__ wB,
    const float* __restrict__ ab, bf16* __restrict__ out, int Fi, int Fo) {
  __shared__ ushort aL[8][264];   // span 258, pad 264
  __shared__ ushort bL[128][36];
  int fo0 = blockIdx.x * 128, co0 = blockIdx.y * 128, b = blockIdx.z;
  int tid = threadIdx.x;
  int w = tid >> 6, l = tid & 63;
  int m0 = (w >> 1) * 64, n0 = (w & 1) * 64;
  int row = l & 15, kq = l >> 4;
  f32x4 acc[4][4];
#pragma unroll
  for (int i = 0; i < 4; ++i)
#pragma unroll
    for (int j = 0; j < 4; ++j) acc[i][j] = {0.f, 0.f, 0.f, 0.f};
  int fi0 = fo0 * 2 - 1;
  const bf16* ib = in + (size_t)b * 512 * Fi;
  int sco = tid >> 1, shalf = tid & 1;
  for (int step = 0; step < 64; ++step) {
    int ci0 = step * 8;
    int k0 = step * 32;
    __syncthreads();
    for (int u = tid; u < 1032; u += 256) {
      int ci = u / 129, pp = (u % 129) * 2;
      float a = ab[ci0 + ci], bb = ab[512 + ci0 + ci];
      const bf16* zr = ib + (size_t)(ci0 + ci) * Fi;
      uint pk = 0;
#pragma unroll
      for (int e = 0; e < 2; ++e) {
        int fi = fi0 + pp + e;
        float v = 0.f;
        if ((unsigned)fi < (unsigned)Fi)
          v = fmaxf(fmaf(a, bf2f(zr[fi]), bb), 0.f);
        pk |= (uint)bfbits(v) << (16 * e);
      }
      *(uint*)&aL[ci][pp] = pk;
    }
    {
      const uint2* src = (const uint2*)(wB + (size_t)(co0 + sco) * 2048 + k0 + shalf * 16);
      uint2* dst = (uint2*)&bL[sco][shalf * 16];
      dst[0] = src[0]; dst[1] = src[1]; dst[2] = src[2]; dst[3] = src[3];
    }
    __syncthreads();
    bf16x8 af[4], bfr[4];
#pragma unroll
    for (int mi = 0; mi < 4; ++mi) {
      int p0 = (m0 + mi * 16 + row) * 2;
      const char* base = (const char*)&aL[0][0];
      const uint* r0p = (const uint*)(base + (2 * kq) * 528 + p0 * 2);
      const uint* r1p = (const uint*)(base + (2 * kq + 1) * 528 + p0 * 2);
      FragU f; f.u = make_uint4(r0p[0], r0p[1], r1p[0], r1p[1]);
      af[mi] = f.v;
    }
#pragma unroll
    for (int ni = 0; ni < 4; ++ni) {
      int col = n0 + ni * 16 + row;
      const uint2* bp = (const uint2*)((const char*)&bL[0][0] + col * 72 + kq * 16);
      uint2 b0 = bp[0], b1 = bp[1];
      FragU f; f.u = make_uint4(b0.x, b0.y, b1.x, b1.y);
      bfr[ni] = f.v;
    }
#pragma unroll
    for (int mi = 0; mi < 4; ++mi)
#pragma unroll
      for (int ni = 0; ni < 4; ++ni)
        acc[mi][ni] = __builtin_amdgcn_mfma_f32_16x16x32_bf16(af[mi], bfr[ni], acc[mi][ni], 0, 0, 0);
  }
  size_t ob = (size_t)b * 512;
#pragma unroll
  for (int mi = 0; mi < 4; ++mi)
#pragma unroll
    for (int ni = 0; ni < 4; ++ni)
#pragma unroll
      for (int r = 0; r < 4; ++r) {
        int m = m0 + mi * 16 + kq * 4 + r;
        int n = n0 + ni * 16 + row;
        out[(ob + co0 + n) * Fo + fo0 + m] = f2bf(acc[mi][ni][r]);
      }
}

// ---------------------------------------------------------------- gi GEMM (VALU, small)
__global__ __launch_bounds__(256) void gi_kernel(
    const bf16* __restrict__ z5, const float* __restrict__ wihT,
    const float* __restrict__ bih, const float* __restrict__ ab,
    float* __restrict__ gi) {
  __shared__ float a_lds[8][64];
  __shared__ float w_lds[8][128];
  int t0 = blockIdx.x * 64, j0 = blockIdx.y * 128, b = blockIdx.z;
  int tid = threadIdx.x, tx = tid & 15, ty = tid >> 4;
  float acc[4][8] = {};
  for (int ci0 = 0; ci0 < 512; ci0 += 8) {
    __syncthreads();
    for (int i = tid; i < 512; i += 256) {
      int ci = i >> 6, t = i & 63;
      float v = bf2f(z5[((size_t)b * 512 + ci0 + ci) * 256 + t0 + t]);
      a_lds[ci][t] = fmaxf(fmaf(ab[ci0 + ci], v, ab[512 + ci0 + ci]), 0.f);
    }
    {
      int i = tid * 4;
      int ci = i >> 7, j = i & 127;
      *(float4*)&w_lds[ci][j] = *(const float4*)&wihT[(size_t)(ci0 + ci) * 768 + j0 + j];
    }
    __syncthreads();
#pragma unroll
    for (int ci = 0; ci < 8; ++ci) {
      float av[4];
#pragma unroll
      for (int j = 0; j < 4; ++j) av[j] = a_lds[ci][tx + 16 * j];
      const float* wp = &w_lds[ci][ty * 8];
      float4 w0 = *(const float4*)wp;
      float4 w1 = *(const float4*)(wp + 4);
      float wv[8] = {w0.x, w0.y, w0.z, w0.w, w1.x, w1.y, w1.z, w1.w};
#pragma unroll
      for (int j = 0; j < 4; ++j)
#pragma unroll
        for (int cc = 0; cc < 8; ++cc)
          acc[j][cc] = fmaf(av[j], wv[cc], acc[j][cc]);
    }
  }
  float bv[8];
#pragma unroll
  for (int cc = 0; cc < 8; ++cc) bv[cc] = bih[j0 + ty * 8 + cc];
#pragma unroll
  for (int j = 0; j < 4; ++j) {
    int rowi = t0 + tx + 16 * j;
    float4 s0 = {acc[j][0] + bv[0], acc[j][1] + bv[1], acc[j][2] + bv[2], acc[j][3] + bv[3]};
    float4 s1 = {acc[j][4] + bv[4], acc[j][5] + bv[5], acc[j][6] + bv[6], acc[j][7] + bv[7]};
    float* gp = &gi[((size_t)b * 256 + rowi) * 768 + j0 + ty * 8];
    *(float4*)gp = s0;
    *(float4*)(gp + 4) = s1;
  }
}

// ---------------------------------------------------------------- GRU (coalesced packed weights)
__global__ __launch_bounds__(256) void gru_kernel(
    const float* __restrict__ gi, const uint* __restrict__ P,
    const float* __restrict__ bhh, const int* __restrict__ tsamp,
    float* __restrict__ c_t) {
  int b = blockIdx.x;
  int j = threadIdx.x;
  __shared__ float h[256];
  h[j] = 0.f;
  int Tb = tsamp[b];
  float bhr = bhh[j], bhz = bhh[256 + j], bhn = bhh[512 + j];
  const float* gib = gi + (size_t)b * 256 * 768;
  __syncthreads();
  for (int t = 0; t <= Tb; ++t) {
    const float* git = gib + t * 768;
    float dr = 0.f, dz = 0.f, dn = 0.f;
#pragma unroll 4
    for (int p = 0; p < 128; ++p) {
      uint ur = P[p * 768 + j];
      uint uz = P[p * 768 + 256 + j];
      uint un = P[p * 768 + 512 + j];
      float2 hh = *(const float2*)&h[2 * p];
      dr = fmaf(__uint_as_float(ur << 16), hh.x, dr);
      dr = fmaf(__uint_as_float(ur & 0xffff0000u), hh.y, dr);
      dz = fmaf(__uint_as_float(uz << 16), hh.x, dz);
      dz = fmaf(__uint_as_float(uz & 0xffff0000u), hh.y, dz);
      dn = fmaf(__uint_as_float(un << 16), hh.x, dn);
      dn = fmaf(__uint_as_float(un & 0xffff0000u), hh.y, dn);
    }
    float xr_ = git[j], xz_ = git[256 + j], xn_ = git[512 + j];
    float r = 1.f / (1.f + __expf(-(xr_ + dr + bhr)));
    float zg = 1.f / (1.f + __expf(-(xz_ + dz + bhz)));
    float n = tanhf(fmaf(r, dn + bhn, xn_));
    float hj = h[j];
    float hnew = fmaf(zg, hj - n, n);
    __syncthreads();
    h[j] = hnew;
    __syncthreads();
  }
  c_t[b * 256 + j] = h[j];
}

// ---------------------------------------------------------------- pred
__global__ __launch_bounds__(256) void pred_kernel(
    const float* __restrict__ c_t, const float* __restrict__ wk,
    const float* __restrict__ bk, float* __restrict__ pred) {
  int tp = blockIdx.x >> 5, c = blockIdx.x & 31;
  __shared__ float cl[256];
  cl[threadIdx.x] = c_t[c * 256 + threadIdx.x];
  __syncthreads();
  const float* wkt = wk + (size_t)tp * 512 * 256;
  for (int d = threadIdx.x; d < 512; d += 256) {
    float a = bk[tp * 512 + d];
    const float* wv = wkt + (size_t)d * 256;
    for (int hh = 0; hh < 256; hh += 4) {
      float4 w4 = *(const float4*)&wv[hh];
      a = fmaf(w4.x, cl[hh], a);
      a = fmaf(w4.y, cl[hh + 1], a);
      a = fmaf(w4.z, cl[hh + 2], a);
      a = fmaf(w4.w, cl[hh + 3], a);
    }
    pred[((size_t)tp * 32 + c) * 512 + d] = a;
  }
}

// ---------------------------------------------------------------- totals
__global__ __launch_bounds__(256) void totals_kernel(
    const bf16* __restrict__ z5, const float* __restrict__ ab,
    const int* __restrict__ tsamp, const float* __restrict__ pred,
    float* __restrict__ totals) {
  int tp = blockIdx.x >> 5, b = blockIdx.x & 31;
  __shared__ float el[512];
  __shared__ float red[256];
  int tb = tsamp[b] + 1 + tp;
  for (int d = threadIdx.x; d < 512; d += 256) {
    float v = bf2f(z5[((size_t)b * 512 + d) * 256 + tb]);
    el[d] = fmaxf(fmaf(ab[d], v, ab[512 + d]), 0.f);
  }
  __syncthreads();
  int c = threadIdx.x & 31, chunk = threadIdx.x >> 5;
  const float* pr = pred + ((size_t)tp * 32 + c) * 512 + chunk * 64;
  const float* ep = &el[chunk * 64];
  float a = 0.f;
#pragma unroll 8
  for (int d = 0; d < 64; ++d) a = fmaf(pr[d], ep[d], a);
  red[threadIdx.x] = a;
  __syncthreads();
  if (threadIdx.x < 32) {
    float s = 0.f;
#pragma unroll
    for (int k = 0; k < 8; ++k) s += red[k * 32 + threadIdx.x];
    totals[((size_t)tp * 32 + b) * 32 + threadIdx.x] = s;
  }
}

// ---------------------------------------------------------------- final
__global__ __launch_bounds__(384) void final_kernel(const float* __restrict__ totals,
                                                    float* __restrict__ out) {
  __shared__ float adj[12 * 32 * 32];
  __shared__ float tr_red[384];
  __shared__ int cr_red[384];
  int tid = threadIdx.x;
  for (int i = tid; i < 12288; i += 384) adj[i] = totals[i];
  __syncthreads();
  int tp = tid / 32, b = tid % 32;
  float* row = &adj[(tp * 32 + b) * 32];
  float mx = row[0];
#pragma unroll
  for (int c = 1; c < 32; ++c) mx = fmaxf(mx, row[c]);
  float se = 0.f;
  for (int c = 0; c < 32; ++c) se += expf(row[c] - mx);
  float lse = mx + logf(se);
  float tr = row[b] - lse;
  __syncthreads();
  for (int c = 0; c < 32; ++c) row[c] -= lse;
  __syncthreads();
  int c = b;
  float best = adj[(tp * 32 + 0) * 32 + c];
  int bi = 0;
  for (int bb = 1; bb < 32; ++bb) {
    float v = adj[(tp * 32 + bb) * 32 + c];
    if (v > best) { best = v; bi = bb; }
  }
  tr_red[tid] = tr;
  cr_red[tid] = (bi == c) ? 1 : 0;
  __syncthreads();
  if (tid == 0) {
    float ts_ = 0.f;
    int cs = 0;
    for (int i = 0; i < 384; ++i) { ts_ += tr_red[i]; cs += cr_red[i]; }
    out[0] = (float)cs / 32.0f;
    out[1] = ts_ / (-384.0f);
  }
}

// ================================================================ launcher
extern "C" void kernel_launch(void* const* d_in, const int* in_sizes, int n_in,
                              void* d_out, int out_size, void* d_ws, size_t ws_size,
                              hipStream_t stream) {
  const float* x = (const float*)d_in[0];
  const int* tsamp = (const int*)d_in[1];
  const float* w1 = (const float*)d_in[2];
  const float* w2 = (const float*)d_in[3];
  const float* w3 = (const float*)d_in[4];
  const float* w4 = (const float*)d_in[5];
  const float* w5 = (const float*)d_in[6];
  const float* gg[5] = {(const float*)d_in[7], (const float*)d_in[9], (const float*)d_in[11],
                        (const float*)d_in[13], (const float*)d_in[15]};
  const float* bee[5] = {(const float*)d_in[8], (const float*)d_in[10], (const float*)d_in[12],
                         (const float*)d_in[14], (const float*)d_in[16]};
  const float* wih = (const float*)d_in[17];
  const float* whh = (const float*)d_in[18];
  const float* bih = (const float*)d_in[19];
  const float* bhh = (const float*)d_in[20];
  const float* wk = (const float*)d_in[21];
  const float* bk = (const float*)d_in[22];
  float* out = (float*)d_out;

  char* base = (char*)d_ws;
  size_t off = 0;
  auto alloc = [&](size_t bytes) -> char* {
    char* r = base + off;
    off = (off + bytes + 255) & ~(size_t)255;
    return r;
  };
  // S1: z1n chunk (67.2MB) -> z3raw -> gi.  S2: z2raw (67MB) -> z4raw.
  char* S1 = alloc((size_t)8 * 512 * 8208 * 2);
  char* S2 = alloc((size_t)32 * 512 * 2048 * 2);
  bf16* z1n = (bf16*)S1;
  bf16* z2r = (bf16*)S2;
  bf16* z3r = (bf16*)S1;
  bf16* z4r = (bf16*)S2;
  float* gi = (float*)S1;                             // 25.2MB
  bf16* z5 = (bf16*)alloc((size_t)4194304 * 2);
  bf16* wB2 = (bf16*)alloc((size_t)2097152 * 2);
  bf16* wB3 = (bf16*)alloc((size_t)1048576 * 2);
  bf16* wB4 = (bf16*)alloc((size_t)1048576 * 2);
  bf16* wB5 = (bf16*)alloc((size_t)1048576 * 2);
  float* wihT = (float*)alloc((size_t)393216 * 4);
  uint* whhP = (uint*)alloc((size_t)98304 * 4);
  float* stats = (float*)alloc(5 * 1024 * 4);
  float* ab = (float*)alloc(5 * 1024 * 4);
  float* ct = (float*)alloc(8192 * 4);
  float* pred = (float*)alloc(196608 * 4);
  float* totals = (float*)alloc(12288 * 4);
  (void)ws_size;

  hipMemsetAsync(stats, 0, 5 * 1024 * 4, stream);

  cvt_bf16_kernel<<<8192, 256, 0, stream>>>(w2, wB2, 2097152);
  cvt_bf16_kernel<<<4096, 256, 0, stream>>>(w3, wB3, 1048576);
  cvt_bf16_kernel<<<4096, 256, 0, stream>>>(w4, wB4, 1048576);
  cvt_bf16_kernel<<<4096, 256, 0, stream>>>(w5, wB5, 1048576);
  transpose_kernel<<<dim3(8, 12), 256, 0, stream>>>(wih, wihT, 768, 512);
  pack_whh_kernel<<<384, 256, 0, stream>>>(whh, whhP);

  stats1_kernel<<<dim3(16, 32), 256, 0, stream>>>(x, w1, stats);
  finalize_kernel<<<1, 512, 0, stream>>>(stats, gg[0], bee[0], 1.f / 262144.f, ab);

  for (int ch = 0; ch < 4; ++ch) {
    norm1_kernel<<<dim3(33, 8), 256, 0, stream>>>(x, w1, ab, z1n, ch * 8);
    conv2_mfma<<<dim3(16, 4, 8), 256, 0, stream>>>(z1n, wB2, z2r, ch * 8);
  }
  stats_kernel<<<16384, 256, 0, stream>>>(z2r, 2048, stats + 1024);
  finalize_kernel<<<1, 512, 0, stream>>>(stats + 1024, gg[1], bee[1], 1.f / 65536.f, ab + 1024);

  convN_mfma<<<dim3(8, 4, 32), 256, 0, stream>>>(z2r, wB3, ab + 1024, z3r, 2048, 1024);
  stats_kernel<<<16384, 256, 0, stream>>>(z3r, 1024, stats + 2048);
  finalize_kernel<<<1, 512, 0, stream>>>(stats + 2048, gg[2], bee[2], 1.f / 32768.f, ab + 2048);

  convN_mfma<<<dim3(4, 4, 32), 256, 0, stream>>>(z3r, wB4, ab + 2048, z4r, 1024, 512);
  stats_kernel<<<16384, 256, 0, stream>>>(z4r, 512, stats + 3072);
  finalize_kernel<<<1, 512, 0, stream>>>(stats + 3072, gg[3], bee[3], 1.f / 16384.f, ab + 3072);

  convN_mfma<<<dim3(2, 4, 32), 256, 0, stream>>>(z4r, wB5, ab + 3072, z5, 512, 256);
  stats_kernel<<<16384, 256, 0, stream>>>(z5, 256, stats + 4096);
  finalize_kernel<<<1, 512, 0, stream>>>(stats + 4096, gg[4], bee[4], 1.f / 8192.f, ab + 4096);

  gi_kernel<<<dim3(4, 6, 32), 256, 0, stream>>>(z5, wihT, bih, ab + 4096, gi);
  gru_kernel<<<32, 256, 0, stream>>>(gi, whhP, bhh, tsamp, ct);
  pred_kernel<<<384, 256, 0, stream>>>(ct, wk, bk, pred);
  totals_kernel<<<384, 256, 0, stream>>>(z5, ab + 4096, tsamp, pred, totals);
  final_kernel<<<1, 384, 0, stream>>>(totals, out);
}